// Round 1
// baseline (30221.341 us; speedup 1.0000x reference)
//
#include <hip/hip_runtime.h>
#include <math.h>

#define N_PTS 4096
#define DD 1024
#define DL 64
#define NEDGE (N_PTS - 1)

// ---------------- ae_loss + row squared norms of y_true ----------------
// One block per row; 256 threads x float4 = 1024 floats.
__global__ __launch_bounds__(256) void ae_sq_kernel(const float* __restrict__ yt,
                                                    const float* __restrict__ yp,
                                                    float* __restrict__ out,
                                                    float* __restrict__ sqD) {
  int row = blockIdx.x, tid = threadIdx.x;
  const float4* a = (const float4*)(yt + (size_t)row * DD);
  const float4* b = (const float4*)(yp + (size_t)row * DD);
  float4 va = a[tid], vb = b[tid];
  float e0 = va.x - vb.x, e1 = va.y - vb.y, e2 = va.z - vb.z, e3 = va.w - vb.w;
  float se = e0 * e0 + e1 * e1 + e2 * e2 + e3 * e3;
  float ss = va.x * va.x + va.y * va.y + va.z * va.z + va.w * va.w;
  for (int off = 32; off > 0; off >>= 1) {
    se += __shfl_down(se, off);
    ss += __shfl_down(ss, off);
  }
  __shared__ float sse[4], sss[4];
  int lane = tid & 63, w = tid >> 6;
  if (lane == 0) { sse[w] = se; sss[w] = ss; }
  __syncthreads();
  if (tid == 0) {
    float tse = sse[0] + sse[1] + sse[2] + sse[3];
    float tss = sss[0] + sss[1] + sss[2] + sss[3];
    out[row] = tse * (1.0f / DD);
    sqD[row] = tss;
  }
}

// ---------------- row squared norms of latent (64 wide) ----------------
// One wave per row; 4 rows per block.
__global__ __launch_bounds__(256) void sql_kernel(const float* __restrict__ lat,
                                                  float* __restrict__ sqL) {
  int row = blockIdx.x * 4 + (threadIdx.x >> 6);
  int lane = threadIdx.x & 63;
  float v = lat[(size_t)row * DL + lane];
  float s = v * v;
  for (int off = 32; off > 0; off >>= 1) s += __shfl_down(s, off);
  if (lane == 0) sqL[row] = s;
}

// ---------------- distance-matrix GEMM (symmetric, upper-tri blocks) ----------------
// C = X @ X^T -> dist[i][j] = sqrt(max(sq[i]+sq[j]-2*dot,0)). 64x64 tile / block,
// 256 threads, 4x4 microtile, K-tile 16. Writes both (i,j) and (j,i).
__global__ __launch_bounds__(256) void dist_gemm(const float* __restrict__ X, int K,
                                                 const float* __restrict__ sq,
                                                 float* __restrict__ dist,
                                                 unsigned int* __restrict__ maxbits,
                                                 int do_max) {
  int bj = blockIdx.x, bi = blockIdx.y;
  if (bi > bj) return;
  __shared__ float As[64][17];
  __shared__ float Bs[16][65];
  int tid = threadIdx.x;
  int tx = tid & 15, ty = tid >> 4;
  float acc[4][4] = {{0.f, 0.f, 0.f, 0.f}, {0.f, 0.f, 0.f, 0.f},
                     {0.f, 0.f, 0.f, 0.f}, {0.f, 0.f, 0.f, 0.f}};
  int row0 = bi * 64, col0 = bj * 64;
  for (int k0 = 0; k0 < K; k0 += 16) {
#pragma unroll
    for (int l = 0; l < 4; ++l) {
      int idx = tid + l * 256;
      int r = idx >> 4, c = idx & 15;
      As[r][c] = X[(size_t)(row0 + r) * K + k0 + c];
      Bs[c][r] = X[(size_t)(col0 + r) * K + k0 + c];
    }
    __syncthreads();
#pragma unroll
    for (int kk = 0; kk < 16; ++kk) {
      float a0 = As[ty * 4 + 0][kk], a1 = As[ty * 4 + 1][kk];
      float a2 = As[ty * 4 + 2][kk], a3 = As[ty * 4 + 3][kk];
      float b0 = Bs[kk][tx * 4 + 0], b1 = Bs[kk][tx * 4 + 1];
      float b2 = Bs[kk][tx * 4 + 2], b3 = Bs[kk][tx * 4 + 3];
      acc[0][0] += a0 * b0; acc[0][1] += a0 * b1; acc[0][2] += a0 * b2; acc[0][3] += a0 * b3;
      acc[1][0] += a1 * b0; acc[1][1] += a1 * b1; acc[1][2] += a1 * b2; acc[1][3] += a1 * b3;
      acc[2][0] += a2 * b0; acc[2][1] += a2 * b1; acc[2][2] += a2 * b2; acc[2][3] += a2 * b3;
      acc[3][0] += a3 * b0; acc[3][1] += a3 * b1; acc[3][2] += a3 * b2; acc[3][3] += a3 * b3;
    }
    __syncthreads();
  }
  float bmax = 0.f;
#pragma unroll
  for (int r = 0; r < 4; ++r) {
    int i = row0 + ty * 4 + r;
    float si = sq[i];
#pragma unroll
    for (int c = 0; c < 4; ++c) {
      int j = col0 + tx * 4 + c;
      float d2 = si + sq[j] - 2.f * acc[r][c];
      float d = d2 > 0.f ? sqrtf(d2) : 0.f;
      dist[(size_t)i * N_PTS + j] = d;
      dist[(size_t)j * N_PTS + i] = d;
      bmax = fmaxf(bmax, d);
    }
  }
  if (do_max) {
    for (int off = 32; off > 0; off >>= 1) bmax = fmaxf(bmax, __shfl_down(bmax, off));
    if ((tid & 63) == 0) atomicMax(maxbits, __float_as_uint(bmax));
  }
}

// ---------------- Prim's MST, one block per matrix ----------------
// State in LDS: min_dist (f32), min_src (u16), in_tree (u8). 4095 serial steps:
// block-wide masked argmin (tie -> smallest index, matches jnp.argmin), then
// relax with matrix row j (16 KB global read, L2/L3 resident).
__global__ __launch_bounds__(256) void prim_kernel(const float* __restrict__ dist0,
                                                   int2* __restrict__ e0,
                                                   const float* __restrict__ dist1,
                                                   int2* __restrict__ e1) {
  const float* dist = (blockIdx.x == 0) ? dist0 : dist1;
  int2* edges = (blockIdx.x == 0) ? e0 : e1;
  __shared__ float md[N_PTS];
  __shared__ unsigned short ms[N_PTS];
  __shared__ unsigned char it[N_PTS];
  __shared__ float rv[4];
  __shared__ int ri[4];
  __shared__ int curj;
  int tid = threadIdx.x;
  for (int i = tid; i < N_PTS; i += 256) {
    md[i] = dist[i];  // row 0
    ms[i] = 0;
    it[i] = 0;
  }
  if (tid == 0) it[0] = 1;
  __syncthreads();
  for (int step = 0; step < NEDGE; ++step) {
    // masked argmin over md
    float bv = INFINITY;
    int bi = N_PTS;
    for (int i = tid; i < N_PTS; i += 256) {
      float v = it[i] ? INFINITY : md[i];
      if (v < bv) { bv = v; bi = i; }  // strict '<' keeps smallest index per thread
    }
    for (int off = 32; off > 0; off >>= 1) {
      float ov = __shfl_down(bv, off);
      int oi = __shfl_down(bi, off);
      if (ov < bv || (ov == bv && oi < bi)) { bv = ov; bi = oi; }
    }
    int lane = tid & 63, w = tid >> 6;
    if (lane == 0) { rv[w] = bv; ri[w] = bi; }
    __syncthreads();
    if (tid == 0) {
      float v = rv[0];
      int j = ri[0];
      for (int k = 1; k < 4; ++k)
        if (rv[k] < v || (rv[k] == v && ri[k] < j)) { v = rv[k]; j = ri[k]; }
      edges[step] = make_int2((int)ms[j], j);
      it[j] = 1;
      curj = j;
    }
    __syncthreads();
    int j = curj;
    const float* row = dist + (size_t)j * N_PTS;
    for (int i = tid; i < N_PTS; i += 256) {
      float dj = row[i];
      if (!it[i] && dj < md[i]) { md[i] = dj; ms[i] = (unsigned short)j; }
    }
    __syncthreads();
  }
}

// ---------------- edge gather + topo losses, recomputed from points ----------------
// One wave per edge slot; slots [0,NEDGE) = data-MST edges, [NEDGE,2*NEDGE) = latent-MST.
__global__ __launch_bounds__(256) void loss_kernel(const float* __restrict__ yt,
                                                   const float* __restrict__ lat,
                                                   const float* __restrict__ sqD,
                                                   const float* __restrict__ sqL,
                                                   const int2* __restrict__ eD,
                                                   const int2* __restrict__ eL,
                                                   const unsigned int* __restrict__ maxbits,
                                                   const float* __restrict__ latent_norm,
                                                   float* __restrict__ sums) {
  int gw = (blockIdx.x * blockDim.x + threadIdx.x) >> 6;
  int lane = threadIdx.x & 63;
  if (gw >= 2 * NEDGE) return;
  int which = (gw >= NEDGE) ? 1 : 0;
  int2 e = which ? eL[gw - NEDGE] : eD[gw];
  int i = e.x, j = e.y;
  const float4* ai = (const float4*)(yt + (size_t)i * DD);
  const float4* aj = (const float4*)(yt + (size_t)j * DD);
  float dot = 0.f;
#pragma unroll
  for (int t = 0; t < 4; ++t) {
    float4 x = ai[lane + t * 64], y = aj[lane + t * 64];
    dot += x.x * y.x + x.y * y.y + x.z * y.z + x.w * y.w;
  }
  float li = lat[(size_t)i * DL + lane], lj = lat[(size_t)j * DL + lane];
  float dotl = li * lj;
  for (int off = 32; off > 0; off >>= 1) {
    dot += __shfl_down(dot, off);
    dotl += __shfl_down(dotl, off);
  }
  if (lane == 0) {
    float inv_md = 1.f / __uint_as_float(*maxbits);
    float inv_ln = 1.f / latent_norm[0];
    float d2 = sqD[i] + sqD[j] - 2.f * dot;
    float dd = (d2 > 0.f ? sqrtf(d2) : 0.f) * inv_md;
    float l2 = sqL[i] + sqL[j] - 2.f * dotl;
    float ld = (l2 > 0.f ? sqrtf(l2) : 0.f) * inv_ln;
    float df = dd - ld;
    atomicAdd(&sums[which], df * df);
  }
}

// ---------------- broadcast topo loss into output ----------------
__global__ __launch_bounds__(256) void finalize_kernel(float* __restrict__ out,
                                                       const float* __restrict__ sums) {
  int i = blockIdx.x * blockDim.x + threadIdx.x;
  float topo = (sums[0] + sums[1]) * (1.0f / NEDGE);
  out[i] += 0.5f * topo;  // REG_LAMBDA = 0.5
}

extern "C" void kernel_launch(void* const* d_in, const int* in_sizes, int n_in,
                              void* d_out, int out_size, void* d_ws, size_t ws_size,
                              hipStream_t stream) {
  const float* y_true = (const float*)d_in[0];
  const float* latent = (const float*)d_in[1];
  const float* y_pred = (const float*)d_in[2];
  const float* latent_norm = (const float*)d_in[3];
  float* out = (float*)d_out;
  char* ws = (char*)d_ws;

  const size_t MAT = (size_t)N_PTS * N_PTS * sizeof(float);  // 64 MB
  size_t off = 0;
  float* distD = (float*)(ws + off); off += MAT;
  bool parallel = (ws_size >= 2 * MAT + (1 << 20));
  float* distL = distD;
  if (parallel) { distL = (float*)(ws + off); off += MAT; }
  float* sqD = (float*)(ws + off); off += (size_t)N_PTS * 4;
  float* sqL = (float*)(ws + off); off += (size_t)N_PTS * 4;
  int2* eD = (int2*)(ws + off); off += (size_t)NEDGE * 8 + 8;
  int2* eL = (int2*)(ws + off); off += (size_t)NEDGE * 8 + 8;
  unsigned int* maxbits = (unsigned int*)(ws + off);
  float* sums = (float*)(ws + off + 4);

  hipMemsetAsync(maxbits, 0, 32, stream);

  ae_sq_kernel<<<N_PTS, 256, 0, stream>>>(y_true, y_pred, out, sqD);
  sql_kernel<<<N_PTS / 4, 256, 0, stream>>>(latent, sqL);

  dim3 g(N_PTS / 64, N_PTS / 64);
  dist_gemm<<<g, 256, 0, stream>>>(y_true, DD, sqD, distD, maxbits, 1);
  if (parallel) {
    dist_gemm<<<g, 256, 0, stream>>>(latent, DL, sqL, distL, maxbits, 0);
    prim_kernel<<<2, 256, 0, stream>>>(distD, eD, distL, eL);
  } else {
    prim_kernel<<<1, 256, 0, stream>>>(distD, eD, distD, eD);
    dist_gemm<<<g, 256, 0, stream>>>(latent, DL, sqL, distL, maxbits, 0);
    prim_kernel<<<1, 256, 0, stream>>>(distL, eL, distL, eL);
  }
  loss_kernel<<<(2 * NEDGE + 3) / 4, 256, 0, stream>>>(y_true, latent, sqD, sqL, eD, eL,
                                                       maxbits, latent_norm, sums);
  finalize_kernel<<<N_PTS / 256, 256, 0, stream>>>(out, sums);
}

// Round 2
// 1044.119 us; speedup vs baseline: 28.9444x; 28.9444x over previous
//
#include <hip/hip_runtime.h>
#include <math.h>

#define N_PTS 4096
#define DD 1024
#define DL 64
#define NEDGE (N_PTS - 1)
#define B_ROUNDS 12

// ---------------- ae_loss + row squared norms of y_true ----------------
__global__ __launch_bounds__(256) void ae_sq_kernel(const float* __restrict__ yt,
                                                    const float* __restrict__ yp,
                                                    float* __restrict__ out,
                                                    float* __restrict__ sqD) {
  int row = blockIdx.x, tid = threadIdx.x;
  const float4* a = (const float4*)(yt + (size_t)row * DD);
  const float4* b = (const float4*)(yp + (size_t)row * DD);
  float4 va = a[tid], vb = b[tid];
  float e0 = va.x - vb.x, e1 = va.y - vb.y, e2 = va.z - vb.z, e3 = va.w - vb.w;
  float se = e0 * e0 + e1 * e1 + e2 * e2 + e3 * e3;
  float ss = va.x * va.x + va.y * va.y + va.z * va.z + va.w * va.w;
  for (int off = 32; off > 0; off >>= 1) {
    se += __shfl_down(se, off);
    ss += __shfl_down(ss, off);
  }
  __shared__ float sse[4], sss[4];
  int lane = tid & 63, w = tid >> 6;
  if (lane == 0) { sse[w] = se; sss[w] = ss; }
  __syncthreads();
  if (tid == 0) {
    out[row] = (sse[0] + sse[1] + sse[2] + sse[3]) * (1.0f / DD);
    sqD[row] = sss[0] + sss[1] + sss[2] + sss[3];
  }
}

// ---------------- row squared norms of latent ----------------
__global__ __launch_bounds__(256) void sql_kernel(const float* __restrict__ lat,
                                                  float* __restrict__ sqL) {
  int row = blockIdx.x * 4 + (threadIdx.x >> 6);
  int lane = threadIdx.x & 63;
  float v = lat[(size_t)row * DL + lane];
  float s = v * v;
  for (int off = 32; off > 0; off >>= 1) s += __shfl_down(s, off);
  if (lane == 0) sqL[row] = s;
}

// ---------------- distance-matrix GEMM (symmetric, upper-tri blocks) ----------------
__global__ __launch_bounds__(256) void dist_gemm(const float* __restrict__ X, int K,
                                                 const float* __restrict__ sq,
                                                 float* __restrict__ dist,
                                                 unsigned int* __restrict__ maxbits,
                                                 int do_max) {
  int bj = blockIdx.x, bi = blockIdx.y;
  if (bi > bj) return;
  __shared__ float As[64][17];
  __shared__ float Bs[16][65];
  int tid = threadIdx.x;
  int tx = tid & 15, ty = tid >> 4;
  float acc[4][4] = {{0.f, 0.f, 0.f, 0.f}, {0.f, 0.f, 0.f, 0.f},
                     {0.f, 0.f, 0.f, 0.f}, {0.f, 0.f, 0.f, 0.f}};
  int row0 = bi * 64, col0 = bj * 64;
  for (int k0 = 0; k0 < K; k0 += 16) {
#pragma unroll
    for (int l = 0; l < 4; ++l) {
      int idx = tid + l * 256;
      int r = idx >> 4, c = idx & 15;
      As[r][c] = X[(size_t)(row0 + r) * K + k0 + c];
      Bs[c][r] = X[(size_t)(col0 + r) * K + k0 + c];
    }
    __syncthreads();
#pragma unroll
    for (int kk = 0; kk < 16; ++kk) {
      float a0 = As[ty * 4 + 0][kk], a1 = As[ty * 4 + 1][kk];
      float a2 = As[ty * 4 + 2][kk], a3 = As[ty * 4 + 3][kk];
      float b0 = Bs[kk][tx * 4 + 0], b1 = Bs[kk][tx * 4 + 1];
      float b2 = Bs[kk][tx * 4 + 2], b3 = Bs[kk][tx * 4 + 3];
      acc[0][0] += a0 * b0; acc[0][1] += a0 * b1; acc[0][2] += a0 * b2; acc[0][3] += a0 * b3;
      acc[1][0] += a1 * b0; acc[1][1] += a1 * b1; acc[1][2] += a1 * b2; acc[1][3] += a1 * b3;
      acc[2][0] += a2 * b0; acc[2][1] += a2 * b1; acc[2][2] += a2 * b2; acc[2][3] += a2 * b3;
      acc[3][0] += a3 * b0; acc[3][1] += a3 * b1; acc[3][2] += a3 * b2; acc[3][3] += a3 * b3;
    }
    __syncthreads();
  }
  float bmax = 0.f;
#pragma unroll
  for (int r = 0; r < 4; ++r) {
    int i = row0 + ty * 4 + r;
    float si = sq[i];
#pragma unroll
    for (int c = 0; c < 4; ++c) {
      int j = col0 + tx * 4 + c;
      float d2 = si + sq[j] - 2.f * acc[r][c];
      float d = d2 > 0.f ? sqrtf(d2) : 0.f;
      dist[(size_t)i * N_PTS + j] = d;
      dist[(size_t)j * N_PTS + i] = d;
      bmax = fmaxf(bmax, d);
    }
  }
  if (do_max) {
    for (int off = 32; off > 0; off >>= 1) bmax = fmaxf(bmax, __shfl_down(bmax, off));
    if ((tid & 63) == 0) atomicMax(maxbits, __float_as_uint(bmax));
  }
}

// ---------------- Boruvka MST ----------------
// Edge total order: key = distBits<<24 | min(i,j)<<12 | max(i,j)  (56 bits).
// Unique keys -> unique MST -> matches reference Prim's MST (modulo exact fp32
// distance ties, which the loss tolerates).

__global__ __launch_bounds__(256) void boruvka_init(unsigned short* __restrict__ comp,
                                                    unsigned long long* __restrict__ bestKey,
                                                    int* __restrict__ numRoots,
                                                    int* __restrict__ edgeCnt) {
  int i = blockIdx.x * 256 + threadIdx.x;
  if (i < N_PTS) {
    comp[i] = (unsigned short)i;
    comp[N_PTS + i] = (unsigned short)i;
    bestKey[i] = ~0ULL;
    bestKey[N_PTS + i] = ~0ULL;
  }
  if (i == 0) {
    numRoots[0] = N_PTS; numRoots[1] = N_PTS;
    edgeCnt[0] = 0; edgeCnt[1] = 0;
  }
}

// Per-row scan for min outgoing edge; per-component reduce via atomicMin u64.
// 4 rows per block (one wave each); comp labels cached in LDS.
__global__ __launch_bounds__(256) void boruvka_scan(const float* __restrict__ dist,
                                                    const unsigned short* __restrict__ comp,
                                                    unsigned long long* __restrict__ bestKey,
                                                    const int* __restrict__ numRoots) {
  int inst = blockIdx.y;
  if (numRoots[inst] <= 1) return;
  dist += (size_t)inst * N_PTS * N_PTS;
  comp += (size_t)inst * N_PTS;
  bestKey += (size_t)inst * N_PTS;
  __shared__ unsigned short comp_s[N_PTS];
  int tid = threadIdx.x;
  for (int i = tid; i < N_PTS; i += 256) comp_s[i] = comp[i];
  __syncthreads();
  int wave = tid >> 6, lane = tid & 63;
  int row = blockIdx.x * 4 + wave;
  unsigned short myc = comp_s[row];
  const float* r = dist + (size_t)row * N_PTS;
  unsigned int bb = 0xFFFFFFFFu;
  int bj = N_PTS;
#pragma unroll 4
  for (int t = 0; t < 64; ++t) {
    int c = lane + t * 64;
    float v = r[c];
    unsigned int b = __float_as_uint(v);
    if (comp_s[c] != myc && b < bb) { bb = b; bj = c; }  // strict < : smallest c wins ties
  }
  for (int off = 32; off > 0; off >>= 1) {
    unsigned int ob = __shfl_down(bb, off);
    int oj = __shfl_down(bj, off);
    if (ob < bb || (ob == bb && oj < bj)) { bb = ob; bj = oj; }
  }
  if (lane == 0 && bj < N_PTS) {
    int lo = row < bj ? row : bj, hi = row < bj ? bj : row;
    unsigned long long key = ((unsigned long long)bb << 24) |
                             ((unsigned long long)lo << 12) | (unsigned long long)hi;
    atomicMin(&bestKey[myc], key);
  }
}

// One block per instance: hooking (mutual 2-cycles broken toward smaller root),
// edge emission, pointer-jumping compression, comp relabel, root count, key reset.
__global__ __launch_bounds__(256) void boruvka_merge(unsigned short* __restrict__ comp,
                                                     unsigned long long* __restrict__ bestKey,
                                                     int* __restrict__ numRoots,
                                                     int2* __restrict__ edges,
                                                     int* __restrict__ edgeCnt) {
  int inst = blockIdx.x;
  if (numRoots[inst] <= 1) return;
  comp += (size_t)inst * N_PTS;
  bestKey += (size_t)inst * N_PTS;
  edges += (size_t)inst * NEDGE;
  __shared__ unsigned short comp_s[N_PTS];
  __shared__ int parent_s[N_PTS];
  __shared__ int rootCnt;
  int tid = threadIdx.x;
  if (tid == 0) rootCnt = 0;
  for (int i = tid; i < N_PTS; i += 256) comp_s[i] = comp[i];
  __syncthreads();
  for (int c = tid; c < N_PTS; c += 256) {
    int p = c;
    if (comp_s[c] == c) {  // root
      unsigned long long key = bestKey[c];
      if (key != ~0ULL) {
        int lo = (int)((key >> 12) & 0xFFF), hi = (int)(key & 0xFFF);
        int c2 = (comp_s[lo] == c) ? comp_s[hi] : comp_s[lo];
        bool mutual = (bestKey[c2] == key);
        bool add;
        if (mutual) {
          if (c < c2) add = true;         // stay root, owns the shared edge
          else { p = c2; add = false; }
        } else { p = c2; add = true; }
        if (add) {
          int idx = atomicAdd(&edgeCnt[inst], 1);
          edges[idx] = make_int2(lo, hi);
        }
        bestKey[c] = ~0ULL;  // reset for next round
      }
    }
    parent_s[c] = p;
  }
  __syncthreads();
  for (int it = 0; it < 12; ++it) {  // pointer jumping (races are benign/monotone)
    for (int c = tid; c < N_PTS; c += 256) parent_s[c] = parent_s[parent_s[c]];
    __syncthreads();
  }
  int local = 0;
  for (int c = tid; c < N_PTS; c += 256) {
    comp[c] = (unsigned short)parent_s[comp_s[c]];
    if (comp_s[c] == c && parent_s[c] == c) local++;
  }
  atomicAdd(&rootCnt, local);
  __syncthreads();
  if (tid == 0) numRoots[inst] = rootCnt;
}

// ---------------- edge gather + topo losses, recomputed from points ----------------
__global__ __launch_bounds__(256) void loss_kernel(const float* __restrict__ yt,
                                                   const float* __restrict__ lat,
                                                   const float* __restrict__ sqD,
                                                   const float* __restrict__ sqL,
                                                   const int2* __restrict__ eD,
                                                   const int2* __restrict__ eL,
                                                   const unsigned int* __restrict__ maxbits,
                                                   const float* __restrict__ latent_norm,
                                                   float* __restrict__ sums) {
  int gw = (blockIdx.x * blockDim.x + threadIdx.x) >> 6;
  int lane = threadIdx.x & 63;
  if (gw >= 2 * NEDGE) return;
  int which = (gw >= NEDGE) ? 1 : 0;
  int2 e = which ? eL[gw - NEDGE] : eD[gw];
  int i = e.x, j = e.y;
  const float4* ai = (const float4*)(yt + (size_t)i * DD);
  const float4* aj = (const float4*)(yt + (size_t)j * DD);
  float dot = 0.f;
#pragma unroll
  for (int t = 0; t < 4; ++t) {
    float4 x = ai[lane + t * 64], y = aj[lane + t * 64];
    dot += x.x * y.x + x.y * y.y + x.z * y.z + x.w * y.w;
  }
  float li = lat[(size_t)i * DL + lane], lj = lat[(size_t)j * DL + lane];
  float dotl = li * lj;
  for (int off = 32; off > 0; off >>= 1) {
    dot += __shfl_down(dot, off);
    dotl += __shfl_down(dotl, off);
  }
  if (lane == 0) {
    float inv_md = 1.f / __uint_as_float(*maxbits);
    float inv_ln = 1.f / latent_norm[0];
    float d2 = sqD[i] + sqD[j] - 2.f * dot;
    float dd = (d2 > 0.f ? sqrtf(d2) : 0.f) * inv_md;
    float l2 = sqL[i] + sqL[j] - 2.f * dotl;
    float ld = (l2 > 0.f ? sqrtf(l2) : 0.f) * inv_ln;
    float df = dd - ld;
    atomicAdd(&sums[which], df * df);
  }
}

__global__ __launch_bounds__(256) void finalize_kernel(float* __restrict__ out,
                                                       const float* __restrict__ sums) {
  int i = blockIdx.x * blockDim.x + threadIdx.x;
  float topo = (sums[0] + sums[1]) * (1.0f / NEDGE);
  out[i] += 0.5f * topo;  // REG_LAMBDA
}

extern "C" void kernel_launch(void* const* d_in, const int* in_sizes, int n_in,
                              void* d_out, int out_size, void* d_ws, size_t ws_size,
                              hipStream_t stream) {
  const float* y_true = (const float*)d_in[0];
  const float* latent = (const float*)d_in[1];
  const float* y_pred = (const float*)d_in[2];
  const float* latent_norm = (const float*)d_in[3];
  float* out = (float*)d_out;
  char* ws = (char*)d_ws;

  const size_t MAT = (size_t)N_PTS * N_PTS * sizeof(float);  // 64 MB
  bool parallel = (ws_size >= 2 * MAT + (2 << 20));
  size_t off = 0;
  float* distD = (float*)(ws + off); off += MAT;
  float* distL = distD;
  if (parallel) { distL = (float*)(ws + off); off += MAT; }
  float* sqD = (float*)(ws + off); off += (size_t)N_PTS * 4;
  float* sqL = (float*)(ws + off); off += (size_t)N_PTS * 4;
  int2* edges = (int2*)(ws + off); off += (size_t)2 * NEDGE * 8 + 16;
  unsigned long long* bestKey = (unsigned long long*)(ws + off); off += (size_t)2 * N_PTS * 8;
  unsigned short* comp = (unsigned short*)(ws + off); off += (size_t)2 * N_PTS * 2;
  int* numRoots = (int*)(ws + off); off += 256;  // misc block
  int* edgeCnt = numRoots + 2;
  unsigned int* maxbits = (unsigned int*)(edgeCnt + 2);
  float* sums = (float*)(maxbits + 1);
  int2* eD = edges;
  int2* eL = edges + NEDGE;

  hipMemsetAsync(numRoots, 0, 256, stream);  // zeros maxbits, sums, counters

  ae_sq_kernel<<<N_PTS, 256, 0, stream>>>(y_true, y_pred, out, sqD);
  sql_kernel<<<N_PTS / 4, 256, 0, stream>>>(latent, sqL);
  boruvka_init<<<N_PTS / 256, 256, 0, stream>>>(comp, bestKey, numRoots, edgeCnt);

  dim3 g(N_PTS / 64, N_PTS / 64);
  dist_gemm<<<g, 256, 0, stream>>>(y_true, DD, sqD, distD, maxbits, 1);
  if (parallel) {
    dist_gemm<<<g, 256, 0, stream>>>(latent, DL, sqL, distL, maxbits, 0);
    for (int r = 0; r < B_ROUNDS; ++r) {
      boruvka_scan<<<dim3(N_PTS / 4, 2), 256, 0, stream>>>(distD, comp, bestKey, numRoots);
      boruvka_merge<<<2, 256, 0, stream>>>(comp, bestKey, numRoots, edges, edgeCnt);
    }
  } else {
    for (int r = 0; r < B_ROUNDS; ++r) {
      boruvka_scan<<<dim3(N_PTS / 4, 1), 256, 0, stream>>>(distD, comp, bestKey, numRoots);
      boruvka_merge<<<1, 256, 0, stream>>>(comp, bestKey, numRoots, edges, edgeCnt);
    }
    dist_gemm<<<g, 256, 0, stream>>>(latent, DL, sqL, distL, maxbits, 0);
    for (int r = 0; r < B_ROUNDS; ++r) {
      boruvka_scan<<<dim3(N_PTS / 4, 1), 256, 0, stream>>>(distL, comp + N_PTS,
                                                           bestKey + N_PTS, numRoots + 1);
      boruvka_merge<<<1, 256, 0, stream>>>(comp + N_PTS, bestKey + N_PTS, numRoots + 1,
                                           edges + NEDGE, edgeCnt + 1);
    }
  }
  loss_kernel<<<(2 * NEDGE + 3) / 4, 256, 0, stream>>>(y_true, latent, sqD, sqL, eD, eL,
                                                       maxbits, latent_norm, sums);
  finalize_kernel<<<N_PTS / 256, 256, 0, stream>>>(out, sums);
}

// Round 3
// 891.081 us; speedup vs baseline: 33.9154x; 1.1717x over previous
//
#include <hip/hip_runtime.h>
#include <math.h>

#define N_PTS 4096
#define DD 1024
#define DL 64
#define NEDGE (N_PTS - 1)
#define B_ROUNDS 12
#define NT 32  // 4096/128 tiles per dim

// ---------------- ae_loss + row squared norms of y_true ----------------
__global__ __launch_bounds__(256) void ae_sq_kernel(const float* __restrict__ yt,
                                                    const float* __restrict__ yp,
                                                    float* __restrict__ out,
                                                    float* __restrict__ sqD) {
  int row = blockIdx.x, tid = threadIdx.x;
  const float4* a = (const float4*)(yt + (size_t)row * DD);
  const float4* b = (const float4*)(yp + (size_t)row * DD);
  float4 va = a[tid], vb = b[tid];
  float e0 = va.x - vb.x, e1 = va.y - vb.y, e2 = va.z - vb.z, e3 = va.w - vb.w;
  float se = e0 * e0 + e1 * e1 + e2 * e2 + e3 * e3;
  float ss = va.x * va.x + va.y * va.y + va.z * va.z + va.w * va.w;
  for (int off = 32; off > 0; off >>= 1) {
    se += __shfl_down(se, off);
    ss += __shfl_down(ss, off);
  }
  __shared__ float sse[4], sss[4];
  int lane = tid & 63, w = tid >> 6;
  if (lane == 0) { sse[w] = se; sss[w] = ss; }
  __syncthreads();
  if (tid == 0) {
    out[row] = (sse[0] + sse[1] + sse[2] + sse[3]) * (1.0f / DD);
    sqD[row] = sss[0] + sss[1] + sss[2] + sss[3];
  }
}

__global__ __launch_bounds__(256) void sql_kernel(const float* __restrict__ lat,
                                                  float* __restrict__ sqL) {
  int row = blockIdx.x * 4 + (threadIdx.x >> 6);
  int lane = threadIdx.x & 63;
  float v = lat[(size_t)row * DL + lane];
  float s = v * v;
  for (int off = 32; off > 0; off >>= 1) s += __shfl_down(s, off);
  if (lane == 0) sqL[row] = s;
}

// ---------------- distance GEMM: 128x128 tile, 8x8 microtile, triangular grid ----------------
// Inner loop: 4 x ds_read_b128 per 64 FMAs. Row/col groups {g*4, 64+g*4} keep all
// LDS reads <=2-way (free). Writes both triangles; atomicMax for global max dist.
__global__ __launch_bounds__(256) void dist_gemm128(const float* __restrict__ X, int K,
                                                    const float* __restrict__ sq,
                                                    float* __restrict__ dist,
                                                    unsigned int* __restrict__ maxbits,
                                                    int do_max) {
  // triangular decode: block b -> (bi, bj), bi <= bj
  int bi = 0, rem = blockIdx.x, span = NT;
  while (rem >= span) { rem -= span; ++bi; --span; }
  int bj = bi + rem;
  int row0 = bi * 128, col0 = bj * 128;

  __shared__ float As[8][128];  // [k][row]
  __shared__ float Bs[8][128];  // [k][col]
  int tid = threadIdx.x;
  int tx = tid & 15, ty = tid >> 4;
  int sr = tid >> 1, sc = (tid & 1) * 4;  // staging: row, k-quad

  float acc[8][8];
#pragma unroll
  for (int r = 0; r < 8; ++r)
#pragma unroll
    for (int c = 0; c < 8; ++c) acc[r][c] = 0.f;

  for (int k0 = 0; k0 < K; k0 += 8) {
    float4 va = *(const float4*)(X + (size_t)(row0 + sr) * K + k0 + sc);
    float4 vb = *(const float4*)(X + (size_t)(col0 + sr) * K + k0 + sc);
    __syncthreads();
    As[sc + 0][sr] = va.x; As[sc + 1][sr] = va.y; As[sc + 2][sr] = va.z; As[sc + 3][sr] = va.w;
    Bs[sc + 0][sr] = vb.x; Bs[sc + 1][sr] = vb.y; Bs[sc + 2][sr] = vb.z; Bs[sc + 3][sr] = vb.w;
    __syncthreads();
#pragma unroll
    for (int kk = 0; kk < 8; ++kk) {
      float4 a0 = *(const float4*)&As[kk][ty * 4];
      float4 a1 = *(const float4*)&As[kk][64 + ty * 4];
      float4 b0 = *(const float4*)&Bs[kk][tx * 4];
      float4 b1 = *(const float4*)&Bs[kk][64 + tx * 4];
      float ar[8] = {a0.x, a0.y, a0.z, a0.w, a1.x, a1.y, a1.z, a1.w};
      float bc[8] = {b0.x, b0.y, b0.z, b0.w, b1.x, b1.y, b1.z, b1.w};
#pragma unroll
      for (int r = 0; r < 8; ++r)
#pragma unroll
        for (int c = 0; c < 8; ++c) acc[r][c] += ar[r] * bc[c];
    }
  }

  int rows[8], cols[8];
#pragma unroll
  for (int g = 0; g < 4; ++g) {
    rows[g] = row0 + ty * 4 + g;
    rows[4 + g] = row0 + 64 + ty * 4 + g;
    cols[g] = col0 + tx * 4 + g;
    cols[4 + g] = col0 + 64 + tx * 4 + g;
  }
  float sqr[8], sqc[8];
#pragma unroll
  for (int g = 0; g < 8; ++g) { sqr[g] = sq[rows[g]]; sqc[g] = sq[cols[g]]; }

  float bmax = 0.f;
#pragma unroll
  for (int r = 0; r < 8; ++r) {
    float d[8];
#pragma unroll
    for (int c = 0; c < 8; ++c) {
      float d2 = sqr[r] + sqc[c] - 2.f * acc[r][c];
      d[c] = d2 > 0.f ? sqrtf(d2) : 0.f;
      bmax = fmaxf(bmax, d[c]);
      dist[(size_t)cols[c] * N_PTS + rows[r]] = d[c];  // lower triangle (scattered)
    }
    float4* p0 = (float4*)(dist + (size_t)rows[r] * N_PTS + cols[0]);
    float4* p1 = (float4*)(dist + (size_t)rows[r] * N_PTS + cols[4]);
    *p0 = make_float4(d[0], d[1], d[2], d[3]);
    *p1 = make_float4(d[4], d[5], d[6], d[7]);
  }
  if (do_max) {
    for (int off = 32; off > 0; off >>= 1) bmax = fmaxf(bmax, __shfl_down(bmax, off));
    if ((tid & 63) == 0) atomicMax(maxbits, __float_as_uint(bmax));
  }
}

// ---------------- Boruvka MST ----------------
// Edge total order: key = distBits<<24 | min(i,j)<<12 | max(i,j)  (56 bits, unique).

__global__ __launch_bounds__(256) void boruvka_init(unsigned short* __restrict__ comp,
                                                    unsigned long long* __restrict__ bestKey,
                                                    int* __restrict__ numRoots,
                                                    int* __restrict__ edgeCnt) {
  int i = blockIdx.x * 256 + threadIdx.x;
  if (i < N_PTS) {
    comp[i] = (unsigned short)i;
    comp[N_PTS + i] = (unsigned short)i;
    bestKey[i] = ~0ULL;
    bestKey[N_PTS + i] = ~0ULL;
  }
  if (i == 0) {
    numRoots[0] = N_PTS; numRoots[1] = N_PTS;
    edgeCnt[0] = 0; edgeCnt[1] = 0;
  }
}

// 4 rows per block (one wave each); float4 row reads; comp labels in LDS.
__global__ __launch_bounds__(256) void boruvka_scan(const float* __restrict__ dist,
                                                    const unsigned short* __restrict__ comp,
                                                    unsigned long long* __restrict__ bestKey,
                                                    const int* __restrict__ numRoots) {
  int inst = blockIdx.y;
  if (numRoots[inst] <= 1) return;
  dist += (size_t)inst * N_PTS * N_PTS;
  comp += (size_t)inst * N_PTS;
  bestKey += (size_t)inst * N_PTS;
  __shared__ unsigned short comp_s[N_PTS];
  int tid = threadIdx.x;
  for (int i = tid; i < N_PTS; i += 256) comp_s[i] = comp[i];
  __syncthreads();
  int wave = tid >> 6, lane = tid & 63;
  int row = blockIdx.x * 4 + wave;
  unsigned int myc = comp_s[row];
  const float4* r4 = (const float4*)(dist + (size_t)row * N_PTS);
  unsigned int bb = 0xFFFFFFFFu;
  int bj = N_PTS;
#pragma unroll 4
  for (int t = 0; t < 16; ++t) {
    int idx = lane + t * 64;  // float4 index; cols 4*idx..4*idx+3
    float4 v = r4[idx];
    uint2 cc = *(const uint2*)(&comp_s[idx * 4]);
    unsigned int c0 = cc.x & 0xFFFFu, c1 = cc.x >> 16;
    unsigned int c2 = cc.y & 0xFFFFu, c3 = cc.y >> 16;
    unsigned int b0 = __float_as_uint(v.x), b1 = __float_as_uint(v.y);
    unsigned int b2 = __float_as_uint(v.z), b3 = __float_as_uint(v.w);
    if (c0 != myc && b0 < bb) { bb = b0; bj = idx * 4; }
    if (c1 != myc && b1 < bb) { bb = b1; bj = idx * 4 + 1; }
    if (c2 != myc && b2 < bb) { bb = b2; bj = idx * 4 + 2; }
    if (c3 != myc && b3 < bb) { bb = b3; bj = idx * 4 + 3; }
  }
  for (int off = 32; off > 0; off >>= 1) {
    unsigned int ob = __shfl_down(bb, off);
    int oj = __shfl_down(bj, off);
    if (ob < bb || (ob == bb && oj < bj)) { bb = ob; bj = oj; }
  }
  if (lane == 0 && bj < N_PTS) {
    int lo = row < bj ? row : bj, hi = row < bj ? bj : row;
    unsigned long long key = ((unsigned long long)bb << 24) |
                             ((unsigned long long)lo << 12) | (unsigned long long)hi;
    atomicMin(&bestKey[myc], key);
  }
}

// One block per instance. Race-free: snapshot ALL bestKey into LDS before any
// reset; hooking decisions read only the snapshot. Mutual 2-cycles share one
// edge (unique keys) -> smaller root keeps it and stays root.
__global__ __launch_bounds__(256) void boruvka_merge(unsigned short* __restrict__ comp,
                                                     unsigned long long* __restrict__ bestKey,
                                                     int* __restrict__ numRoots,
                                                     int2* __restrict__ edges,
                                                     int* __restrict__ edgeCnt) {
  int inst = blockIdx.x;
  if (numRoots[inst] <= 1) return;
  comp += (size_t)inst * N_PTS;
  bestKey += (size_t)inst * N_PTS;
  edges += (size_t)inst * NEDGE;
  __shared__ unsigned short comp_s[N_PTS];
  __shared__ int parent_s[N_PTS];
  __shared__ unsigned long long key_s[N_PTS];
  __shared__ int rootCnt;
  int tid = threadIdx.x;
  if (tid == 0) rootCnt = 0;
  for (int i = tid; i < N_PTS; i += 256) {
    comp_s[i] = comp[i];
    key_s[i] = bestKey[i];
    bestKey[i] = ~0ULL;  // reset for next round; decisions below use key_s only
  }
  __syncthreads();
  for (int c = tid; c < N_PTS; c += 256) {
    int p = c;
    if (comp_s[c] == c) {  // root
      unsigned long long key = key_s[c];
      if (key != ~0ULL) {
        int lo = (int)((key >> 12) & 0xFFF), hi = (int)(key & 0xFFF);
        int c2 = (comp_s[lo] == c) ? comp_s[hi] : comp_s[lo];
        bool mutual = (key_s[c2] == key);
        bool add;
        if (mutual) {
          if (c < c2) add = true;  // stays root, owns the shared edge
          else { p = c2; add = false; }
        } else { p = c2; add = true; }
        if (add) {
          int idx = atomicAdd(&edgeCnt[inst], 1);
          if (idx < NEDGE) edges[idx] = make_int2(lo, hi);
        }
      }
    }
    parent_s[c] = p;
  }
  __syncthreads();
  for (int it = 0; it < 12; ++it) {  // pointer jumping (races benign: monotone)
    for (int c = tid; c < N_PTS; c += 256) parent_s[c] = parent_s[parent_s[c]];
    __syncthreads();
  }
  int local = 0;
  for (int c = tid; c < N_PTS; c += 256) {
    comp[c] = (unsigned short)parent_s[comp_s[c]];
    if (comp_s[c] == c && parent_s[c] == c) local++;
  }
  atomicAdd(&rootCnt, local);
  __syncthreads();
  if (tid == 0) numRoots[inst] = rootCnt;
}

// ---------------- edge gather + topo losses, recomputed from points ----------------
__global__ __launch_bounds__(256) void loss_kernel(const float* __restrict__ yt,
                                                   const float* __restrict__ lat,
                                                   const float* __restrict__ sqD,
                                                   const float* __restrict__ sqL,
                                                   const int2* __restrict__ eD,
                                                   const int2* __restrict__ eL,
                                                   const unsigned int* __restrict__ maxbits,
                                                   const float* __restrict__ latent_norm,
                                                   float* __restrict__ sums) {
  int gw = (blockIdx.x * blockDim.x + threadIdx.x) >> 6;
  int lane = threadIdx.x & 63;
  if (gw >= 2 * NEDGE) return;
  int which = (gw >= NEDGE) ? 1 : 0;
  int2 e = which ? eL[gw - NEDGE] : eD[gw];
  int i = e.x & (N_PTS - 1), j = e.y & (N_PTS - 1);  // clamp: OOB-safety only
  const float4* ai = (const float4*)(yt + (size_t)i * DD);
  const float4* aj = (const float4*)(yt + (size_t)j * DD);
  float dot = 0.f;
#pragma unroll
  for (int t = 0; t < 4; ++t) {
    float4 x = ai[lane + t * 64], y = aj[lane + t * 64];
    dot += x.x * y.x + x.y * y.y + x.z * y.z + x.w * y.w;
  }
  float li = lat[(size_t)i * DL + lane], lj = lat[(size_t)j * DL + lane];
  float dotl = li * lj;
  for (int off = 32; off > 0; off >>= 1) {
    dot += __shfl_down(dot, off);
    dotl += __shfl_down(dotl, off);
  }
  if (lane == 0) {
    float inv_md = 1.f / __uint_as_float(*maxbits);
    float inv_ln = 1.f / latent_norm[0];
    float d2 = sqD[i] + sqD[j] - 2.f * dot;
    float dd = (d2 > 0.f ? sqrtf(d2) : 0.f) * inv_md;
    float l2 = sqL[i] + sqL[j] - 2.f * dotl;
    float ld = (l2 > 0.f ? sqrtf(l2) : 0.f) * inv_ln;
    float df = dd - ld;
    atomicAdd(&sums[which], df * df);
  }
}

__global__ __launch_bounds__(256) void finalize_kernel(float* __restrict__ out,
                                                       const float* __restrict__ sums) {
  int i = blockIdx.x * blockDim.x + threadIdx.x;
  float topo = (sums[0] + sums[1]) * (1.0f / NEDGE);
  out[i] += 0.5f * topo;  // REG_LAMBDA
}

extern "C" void kernel_launch(void* const* d_in, const int* in_sizes, int n_in,
                              void* d_out, int out_size, void* d_ws, size_t ws_size,
                              hipStream_t stream) {
  const float* y_true = (const float*)d_in[0];
  const float* latent = (const float*)d_in[1];
  const float* y_pred = (const float*)d_in[2];
  const float* latent_norm = (const float*)d_in[3];
  float* out = (float*)d_out;
  char* ws = (char*)d_ws;

  const size_t MAT = (size_t)N_PTS * N_PTS * sizeof(float);  // 64 MB
  bool parallel = (ws_size >= 2 * MAT + (2 << 20));
  size_t off = 0;
  float* distD = (float*)(ws + off); off += MAT;
  float* distL = distD;
  if (parallel) { distL = (float*)(ws + off); off += MAT; }
  float* sqD = (float*)(ws + off); off += (size_t)N_PTS * 4;
  float* sqL = (float*)(ws + off); off += (size_t)N_PTS * 4;
  int2* edges = (int2*)(ws + off); off += (size_t)2 * NEDGE * 8 + 16;
  unsigned long long* bestKey = (unsigned long long*)(ws + off); off += (size_t)2 * N_PTS * 8;
  unsigned short* comp = (unsigned short*)(ws + off); off += (size_t)2 * N_PTS * 2;
  int* numRoots = (int*)(ws + off); off += 256;
  int* edgeCnt = numRoots + 2;
  unsigned int* maxbits = (unsigned int*)(edgeCnt + 2);
  float* sums = (float*)(maxbits + 1);
  int2* eD = edges;
  int2* eL = edges + NEDGE;

  hipMemsetAsync(numRoots, 0, 256, stream);

  ae_sq_kernel<<<N_PTS, 256, 0, stream>>>(y_true, y_pred, out, sqD);
  sql_kernel<<<N_PTS / 4, 256, 0, stream>>>(latent, sqL);
  boruvka_init<<<N_PTS / 256, 256, 0, stream>>>(comp, bestKey, numRoots, edgeCnt);

  int tri = NT * (NT + 1) / 2;  // 528
  dist_gemm128<<<tri, 256, 0, stream>>>(y_true, DD, sqD, distD, maxbits, 1);
  if (parallel) {
    dist_gemm128<<<tri, 256, 0, stream>>>(latent, DL, sqL, distL, maxbits, 0);
    for (int r = 0; r < B_ROUNDS; ++r) {
      boruvka_scan<<<dim3(N_PTS / 4, 2), 256, 0, stream>>>(distD, comp, bestKey, numRoots);
      boruvka_merge<<<2, 256, 0, stream>>>(comp, bestKey, numRoots, edges, edgeCnt);
    }
  } else {
    for (int r = 0; r < B_ROUNDS; ++r) {
      boruvka_scan<<<dim3(N_PTS / 4, 1), 256, 0, stream>>>(distD, comp, bestKey, numRoots);
      boruvka_merge<<<1, 256, 0, stream>>>(comp, bestKey, numRoots, edges, edgeCnt);
    }
    dist_gemm128<<<tri, 256, 0, stream>>>(latent, DL, sqL, distL, maxbits, 0);
    for (int r = 0; r < B_ROUNDS; ++r) {
      boruvka_scan<<<dim3(N_PTS / 4, 1), 256, 0, stream>>>(distL, comp + N_PTS,
                                                           bestKey + N_PTS, numRoots + 1);
      boruvka_merge<<<1, 256, 0, stream>>>(comp + N_PTS, bestKey + N_PTS, numRoots + 1,
                                           edges + NEDGE, edgeCnt + 1);
    }
  }
  loss_kernel<<<(2 * NEDGE + 3) / 4, 256, 0, stream>>>(y_true, latent, sqD, sqL, eD, eL,
                                                       maxbits, latent_norm, sums);
  finalize_kernel<<<N_PTS / 256, 256, 0, stream>>>(out, sums);
}

// Round 4
// 409.363 us; speedup vs baseline: 73.8253x; 2.1768x over previous
//
#include <hip/hip_runtime.h>
#include <math.h>

#define N_PTS 4096
#define DD 1024
#define DL 64
#define NEDGE (N_PTS - 1)
#define B_ROUNDS 12
#define NT 32  // 4096/128 tiles per dim

typedef __attribute__((ext_vector_type(8))) short short8;
typedef __attribute__((ext_vector_type(4))) float floatx4;
typedef __attribute__((ext_vector_type(4))) unsigned short ushortx4;

__device__ __forceinline__ unsigned short f2bf(float f) {
  unsigned u = __float_as_uint(f);
  u = u + 0x7FFFu + ((u >> 16) & 1u);  // RNE
  return (unsigned short)(u >> 16);
}

// ---------------- fp32 -> bf16 convert ----------------
__global__ __launch_bounds__(256) void cvt_kernel(const float* __restrict__ x,
                                                  unsigned short* __restrict__ xb, int n4) {
  int i = blockIdx.x * 256 + threadIdx.x;
  if (i >= n4) return;
  float4 v = ((const float4*)x)[i];
  ushortx4 o = {f2bf(v.x), f2bf(v.y), f2bf(v.z), f2bf(v.w)};
  *(ushortx4*)(xb + (size_t)i * 4) = o;
}

// ---------------- ae_loss + row squared norms of y_true ----------------
__global__ __launch_bounds__(256) void ae_sq_kernel(const float* __restrict__ yt,
                                                    const float* __restrict__ yp,
                                                    float* __restrict__ out,
                                                    float* __restrict__ sqD) {
  int row = blockIdx.x, tid = threadIdx.x;
  const float4* a = (const float4*)(yt + (size_t)row * DD);
  const float4* b = (const float4*)(yp + (size_t)row * DD);
  float4 va = a[tid], vb = b[tid];
  float e0 = va.x - vb.x, e1 = va.y - vb.y, e2 = va.z - vb.z, e3 = va.w - vb.w;
  float se = e0 * e0 + e1 * e1 + e2 * e2 + e3 * e3;
  float ss = va.x * va.x + va.y * va.y + va.z * va.z + va.w * va.w;
  for (int off = 32; off > 0; off >>= 1) {
    se += __shfl_down(se, off);
    ss += __shfl_down(ss, off);
  }
  __shared__ float sse[4], sss[4];
  int lane = tid & 63, w = tid >> 6;
  if (lane == 0) { sse[w] = se; sss[w] = ss; }
  __syncthreads();
  if (tid == 0) {
    out[row] = (sse[0] + sse[1] + sse[2] + sse[3]) * (1.0f / DD);
    sqD[row] = sss[0] + sss[1] + sss[2] + sss[3];
  }
}

__global__ __launch_bounds__(256) void sql_kernel(const float* __restrict__ lat,
                                                  float* __restrict__ sqL) {
  int row = blockIdx.x * 4 + (threadIdx.x >> 6);
  int lane = threadIdx.x & 63;
  float v = lat[(size_t)row * DL + lane];
  float s = v * v;
  for (int off = 32; off > 0; off >>= 1) s += __shfl_down(s, off);
  if (lane == 0) sqL[row] = s;
}

// ---------------- bf16 MFMA distance gemm -> u16 matrices ----------------
// 128x128 tile, 4 waves, each wave 64x64 = 4x4 frags of 16x16x32 bf16 MFMA.
// A/B frag layout (m89/m118-verified): elem = X[base + (lane&15)][k = (lane>>4)*8 + j].
// C/D: col = lane&15, row = (lane>>4)*4 + reg  (a row<->col swap would be
// self-correcting here: matrix symmetric, both triangles written).
// dist stored as u16 = fp32 bits >> 16 (order-preserving truncation).
__global__ __launch_bounds__(256) void dist_mfma(const unsigned short* __restrict__ Xb,
                                                 const unsigned short* __restrict__ Lb,
                                                 const float* __restrict__ sqD,
                                                 const float* __restrict__ sqL,
                                                 unsigned short* __restrict__ dD,
                                                 unsigned short* __restrict__ dL,
                                                 unsigned int* __restrict__ maxbits) {
  int inst = blockIdx.y;
  const unsigned short* X = inst ? Lb : Xb;
  const float* sq = inst ? sqL : sqD;
  unsigned short* dist = inst ? dL : dD;
  int K = inst ? DL : DD;

  int bi = 0, rem = blockIdx.x, span = NT;  // triangular decode, bi <= bj
  while (rem >= span) { rem -= span; ++bi; --span; }
  int bj = bi + rem;
  int row0 = bi * 128, col0 = bj * 128;

  __shared__ short As[128 * 40];  // row stride 40 (16B-aligned frags, 2-way banks)
  __shared__ short Bs[128 * 40];
  int tid = threadIdx.x;
  int wave = tid >> 6, lane = tid & 63;
  int m = lane & 15, q = lane >> 4;
  int rw = (wave >> 1) * 64, cw = (wave & 1) * 64;

  floatx4 acc[4][4];
#pragma unroll
  for (int mi = 0; mi < 4; ++mi)
#pragma unroll
    for (int ni = 0; ni < 4; ++ni) acc[mi][ni] = {0.f, 0.f, 0.f, 0.f};

  int s0 = tid, s1 = tid + 256;  // 512 segs/side: row = s>>2, part = s&3
  int r0 = s0 >> 2, p0 = s0 & 3, r1 = s1 >> 2, p1 = s1 & 3;

  for (int k0 = 0; k0 < K; k0 += 32) {
    short8 a0 = *(const short8*)(X + (size_t)(row0 + r0) * K + k0 + p0 * 8);
    short8 a1 = *(const short8*)(X + (size_t)(row0 + r1) * K + k0 + p1 * 8);
    short8 b0 = *(const short8*)(X + (size_t)(col0 + r0) * K + k0 + p0 * 8);
    short8 b1 = *(const short8*)(X + (size_t)(col0 + r1) * K + k0 + p1 * 8);
    __syncthreads();
    *(short8*)&As[r0 * 40 + p0 * 8] = a0;
    *(short8*)&As[r1 * 40 + p1 * 8] = a1;
    *(short8*)&Bs[r0 * 40 + p0 * 8] = b0;
    *(short8*)&Bs[r1 * 40 + p1 * 8] = b1;
    __syncthreads();
    short8 aF[4], bF[4];
#pragma unroll
    for (int mi = 0; mi < 4; ++mi)
      aF[mi] = *(const short8*)&As[(rw + mi * 16 + m) * 40 + q * 8];
#pragma unroll
    for (int ni = 0; ni < 4; ++ni)
      bF[ni] = *(const short8*)&Bs[(cw + ni * 16 + m) * 40 + q * 8];
#pragma unroll
    for (int mi = 0; mi < 4; ++mi)
#pragma unroll
      for (int ni = 0; ni < 4; ++ni)
        acc[mi][ni] = __builtin_amdgcn_mfma_f32_16x16x32_bf16(aF[mi], bF[ni],
                                                              acc[mi][ni], 0, 0, 0);
  }

  float bmax = 0.f;
#pragma unroll
  for (int mi = 0; mi < 4; ++mi) {
    int i0 = row0 + rw + mi * 16 + q * 4;
    float s_i[4] = {sq[i0], sq[i0 + 1], sq[i0 + 2], sq[i0 + 3]};
#pragma unroll
    for (int ni = 0; ni < 4; ++ni) {
      int j = col0 + cw + ni * 16 + m;
      float sj = sq[j];
      ushortx4 tvec;
#pragma unroll
      for (int r = 0; r < 4; ++r) {
        float d2 = s_i[r] + sj - 2.f * acc[mi][ni][r];
        float d = d2 > 0.f ? sqrtf(d2) : 0.f;
        bmax = fmaxf(bmax, d);
        unsigned short u = (unsigned short)(__float_as_uint(d) >> 16);
        dist[(size_t)(i0 + r) * N_PTS + j] = u;  // upper (quad-coalesced 32B)
        tvec[r] = u;
      }
      *(ushortx4*)&dist[(size_t)j * N_PTS + i0] = tvec;  // lower, 8B store
    }
  }
  if (inst == 0) {
    for (int off = 32; off > 0; off >>= 1) bmax = fmaxf(bmax, __shfl_down(bmax, off));
    if (lane == 0) atomicMax(maxbits, __float_as_uint(bmax));
  }
}

// ---------------- Boruvka MST on u16 matrices ----------------
// Edge total order: key = dist16<<24 | min(i,j)<<12 | max(i,j)  (40 bits, unique).

__global__ __launch_bounds__(256) void boruvka_init(unsigned short* __restrict__ comp,
                                                    unsigned long long* __restrict__ bestKey,
                                                    int* __restrict__ numRoots,
                                                    int* __restrict__ edgeCnt) {
  int i = blockIdx.x * 256 + threadIdx.x;
  if (i < N_PTS) {
    comp[i] = (unsigned short)i;
    comp[N_PTS + i] = (unsigned short)i;
    bestKey[i] = ~0ULL;
    bestKey[N_PTS + i] = ~0ULL;
  }
  if (i == 0) {
    numRoots[0] = N_PTS; numRoots[1] = N_PTS;
    edgeCnt[0] = 0; edgeCnt[1] = 0;
  }
}

// 16 rows per block (4 per wave, sequential); ushort8 row reads; comps in LDS.
__global__ __launch_bounds__(256) void boruvka_scan(const unsigned short* __restrict__ dD,
                                                    const unsigned short* __restrict__ dL,
                                                    const unsigned short* __restrict__ comp,
                                                    unsigned long long* __restrict__ bestKey,
                                                    const int* __restrict__ numRoots) {
  int inst = blockIdx.y;
  if (numRoots[inst] <= 1) return;
  const unsigned short* dist = inst ? dL : dD;
  comp += (size_t)inst * N_PTS;
  bestKey += (size_t)inst * N_PTS;
  __shared__ unsigned short comp_s[N_PTS];
  int tid = threadIdx.x;
  for (int i = tid; i < N_PTS; i += 256) comp_s[i] = comp[i];
  __syncthreads();
  int wave = tid >> 6, lane = tid & 63;
  for (int rr = 0; rr < 4; ++rr) {
    int row = blockIdx.x * 16 + wave * 4 + rr;
    unsigned myc = comp_s[row];
    const uint4* r8 = (const uint4*)(dist + (size_t)row * N_PTS);
    unsigned bb = 0xFFFFFFFFu;
    int bj = N_PTS;
    for (int t = 0; t < 8; ++t) {
      int idx = lane + t * 64;  // 8 cols per uint4
      uint4 v = r8[idx];
      uint4 cc = *(const uint4*)&comp_s[idx * 8];
      int j0 = idx * 8;
      unsigned d0 = v.x & 0xFFFFu, d1 = v.x >> 16, d2 = v.y & 0xFFFFu, d3 = v.y >> 16;
      unsigned d4 = v.z & 0xFFFFu, d5 = v.z >> 16, d6 = v.w & 0xFFFFu, d7 = v.w >> 16;
      unsigned c0 = cc.x & 0xFFFFu, c1 = cc.x >> 16, c2 = cc.y & 0xFFFFu, c3 = cc.y >> 16;
      unsigned c4 = cc.z & 0xFFFFu, c5 = cc.z >> 16, c6 = cc.w & 0xFFFFu, c7 = cc.w >> 16;
      if (c0 != myc && d0 < bb) { bb = d0; bj = j0 + 0; }
      if (c1 != myc && d1 < bb) { bb = d1; bj = j0 + 1; }
      if (c2 != myc && d2 < bb) { bb = d2; bj = j0 + 2; }
      if (c3 != myc && d3 < bb) { bb = d3; bj = j0 + 3; }
      if (c4 != myc && d4 < bb) { bb = d4; bj = j0 + 4; }
      if (c5 != myc && d5 < bb) { bb = d5; bj = j0 + 5; }
      if (c6 != myc && d6 < bb) { bb = d6; bj = j0 + 6; }
      if (c7 != myc && d7 < bb) { bb = d7; bj = j0 + 7; }
    }
    for (int off = 32; off > 0; off >>= 1) {
      unsigned ob = __shfl_down(bb, off);
      int oj = __shfl_down(bj, off);
      if (ob < bb || (ob == bb && oj < bj)) { bb = ob; bj = oj; }
    }
    if (lane == 0 && bj < N_PTS) {
      int lo = row < bj ? row : bj, hi = row < bj ? bj : row;
      unsigned long long key = ((unsigned long long)bb << 24) |
                               ((unsigned long long)lo << 12) | (unsigned long long)hi;
      atomicMin(&bestKey[myc], key);
    }
  }
}

// One block per instance, 1024 threads. Race-free: snapshot bestKey into LDS
// before reset; mutual 2-cycles share one edge -> smaller root keeps it.
__global__ __launch_bounds__(1024) void boruvka_merge(unsigned short* __restrict__ comp,
                                                      unsigned long long* __restrict__ bestKey,
                                                      int* __restrict__ numRoots,
                                                      int2* __restrict__ edges,
                                                      int* __restrict__ edgeCnt) {
  int inst = blockIdx.x;
  if (numRoots[inst] <= 1) return;
  comp += (size_t)inst * N_PTS;
  bestKey += (size_t)inst * N_PTS;
  edges += (size_t)inst * NEDGE;
  __shared__ unsigned short comp_s[N_PTS];
  __shared__ int parent_s[N_PTS];
  __shared__ unsigned long long key_s[N_PTS];
  __shared__ int rootCnt;
  int tid = threadIdx.x;
  if (tid == 0) rootCnt = 0;
  for (int i = tid; i < N_PTS; i += 1024) {
    comp_s[i] = comp[i];
    key_s[i] = bestKey[i];
    bestKey[i] = ~0ULL;
  }
  __syncthreads();
  for (int c = tid; c < N_PTS; c += 1024) {
    int p = c;
    if (comp_s[c] == c) {  // root
      unsigned long long key = key_s[c];
      if (key != ~0ULL) {
        int lo = (int)((key >> 12) & 0xFFF), hi = (int)(key & 0xFFF);
        int c2 = (comp_s[lo] == c) ? comp_s[hi] : comp_s[lo];
        bool mutual = (key_s[c2] == key);
        bool add;
        if (mutual) {
          if (c < c2) add = true;
          else { p = c2; add = false; }
        } else { p = c2; add = true; }
        if (add) {
          int idx = atomicAdd(&edgeCnt[inst], 1);
          if (idx < NEDGE) edges[idx] = make_int2(lo, hi);
        }
      }
    }
    parent_s[c] = p;
  }
  __syncthreads();
  for (int it = 0; it < 12; ++it) {  // pointer jumping (monotone races)
    for (int c = tid; c < N_PTS; c += 1024) parent_s[c] = parent_s[parent_s[c]];
    __syncthreads();
  }
  int local = 0;
  for (int c = tid; c < N_PTS; c += 1024) {
    comp[c] = (unsigned short)parent_s[comp_s[c]];
    if (comp_s[c] == c && parent_s[c] == c) local++;
  }
  atomicAdd(&rootCnt, local);
  __syncthreads();
  if (tid == 0) numRoots[inst] = rootCnt;
}

// ---------------- edge gather + topo losses, recomputed exactly from fp32 points ----
__global__ __launch_bounds__(256) void loss_kernel(const float* __restrict__ yt,
                                                   const float* __restrict__ lat,
                                                   const float* __restrict__ sqD,
                                                   const float* __restrict__ sqL,
                                                   const int2* __restrict__ eD,
                                                   const int2* __restrict__ eL,
                                                   const unsigned int* __restrict__ maxbits,
                                                   const float* __restrict__ latent_norm,
                                                   float* __restrict__ sums) {
  int gw = (blockIdx.x * blockDim.x + threadIdx.x) >> 6;
  int lane = threadIdx.x & 63;
  if (gw >= 2 * NEDGE) return;
  int which = (gw >= NEDGE) ? 1 : 0;
  int2 e = which ? eL[gw - NEDGE] : eD[gw];
  int i = e.x & (N_PTS - 1), j = e.y & (N_PTS - 1);
  const float4* ai = (const float4*)(yt + (size_t)i * DD);
  const float4* aj = (const float4*)(yt + (size_t)j * DD);
  float dot = 0.f;
#pragma unroll
  for (int t = 0; t < 4; ++t) {
    float4 x = ai[lane + t * 64], y = aj[lane + t * 64];
    dot += x.x * y.x + x.y * y.y + x.z * y.z + x.w * y.w;
  }
  float li = lat[(size_t)i * DL + lane], lj = lat[(size_t)j * DL + lane];
  float dotl = li * lj;
  for (int off = 32; off > 0; off >>= 1) {
    dot += __shfl_down(dot, off);
    dotl += __shfl_down(dotl, off);
  }
  if (lane == 0) {
    float inv_md = 1.f / __uint_as_float(*maxbits);
    float inv_ln = 1.f / latent_norm[0];
    float d2 = sqD[i] + sqD[j] - 2.f * dot;
    float dd = (d2 > 0.f ? sqrtf(d2) : 0.f) * inv_md;
    float l2 = sqL[i] + sqL[j] - 2.f * dotl;
    float ld = (l2 > 0.f ? sqrtf(l2) : 0.f) * inv_ln;
    float df = dd - ld;
    atomicAdd(&sums[which], df * df);
  }
}

__global__ __launch_bounds__(256) void finalize_kernel(float* __restrict__ out,
                                                       const float* __restrict__ sums) {
  int i = blockIdx.x * blockDim.x + threadIdx.x;
  float topo = (sums[0] + sums[1]) * (1.0f / NEDGE);
  out[i] += 0.5f * topo;  // REG_LAMBDA
}

extern "C" void kernel_launch(void* const* d_in, const int* in_sizes, int n_in,
                              void* d_out, int out_size, void* d_ws, size_t ws_size,
                              hipStream_t stream) {
  const float* y_true = (const float*)d_in[0];
  const float* latent = (const float*)d_in[1];
  const float* y_pred = (const float*)d_in[2];
  const float* latent_norm = (const float*)d_in[3];
  float* out = (float*)d_out;
  char* ws = (char*)d_ws;

  const size_t MAT16 = (size_t)N_PTS * N_PTS * 2;  // 32 MB per u16 matrix
  size_t off = 0;
  unsigned short* dD = (unsigned short*)(ws + off); off += MAT16;
  unsigned short* dL = (unsigned short*)(ws + off); off += MAT16;
  unsigned short* Xb = (unsigned short*)(ws + off); off += (size_t)N_PTS * DD * 2;
  unsigned short* Lb = (unsigned short*)(ws + off); off += (size_t)N_PTS * DL * 2;
  float* sqD = (float*)(ws + off); off += (size_t)N_PTS * 4;
  float* sqL = (float*)(ws + off); off += (size_t)N_PTS * 4;
  int2* edges = (int2*)(ws + off); off += (size_t)2 * NEDGE * 8 + 16;
  unsigned long long* bestKey = (unsigned long long*)(ws + off); off += (size_t)2 * N_PTS * 8;
  unsigned short* comp = (unsigned short*)(ws + off); off += (size_t)2 * N_PTS * 2;
  int* numRoots = (int*)(ws + off); off += 256;
  int* edgeCnt = numRoots + 2;
  unsigned int* maxbits = (unsigned int*)(edgeCnt + 2);
  float* sums = (float*)(maxbits + 1);
  int2* eD = edges;
  int2* eL = edges + NEDGE;

  hipMemsetAsync(numRoots, 0, 256, stream);

  cvt_kernel<<<(N_PTS * DD / 4 + 255) / 256, 256, 0, stream>>>(y_true, Xb, N_PTS * DD / 4);
  cvt_kernel<<<(N_PTS * DL / 4 + 255) / 256, 256, 0, stream>>>(latent, Lb, N_PTS * DL / 4);
  ae_sq_kernel<<<N_PTS, 256, 0, stream>>>(y_true, y_pred, out, sqD);
  sql_kernel<<<N_PTS / 4, 256, 0, stream>>>(latent, sqL);
  boruvka_init<<<N_PTS / 256, 256, 0, stream>>>(comp, bestKey, numRoots, edgeCnt);

  int tri = NT * (NT + 1) / 2;  // 528
  dist_mfma<<<dim3(tri, 2), 256, 0, stream>>>(Xb, Lb, sqD, sqL, dD, dL, maxbits);

  for (int r = 0; r < B_ROUNDS; ++r) {
    boruvka_scan<<<dim3(N_PTS / 16, 2), 256, 0, stream>>>(dD, dL, comp, bestKey, numRoots);
    boruvka_merge<<<2, 1024, 0, stream>>>(comp, bestKey, numRoots, edges, edgeCnt);
  }
  loss_kernel<<<(2 * NEDGE + 3) / 4, 256, 0, stream>>>(y_true, latent, sqD, sqL, eD, eL,
                                                       maxbits, latent_norm, sums);
  finalize_kernel<<<N_PTS / 256, 256, 0, stream>>>(out, sums);
}

// Round 5
// 334.668 us; speedup vs baseline: 90.3024x; 1.2232x over previous
//
#include <hip/hip_runtime.h>
#include <math.h>

#define N_PTS 4096
#define DD 1024
#define DL 64
#define NEDGE (N_PTS - 1)
#define B_ROUNDS 12
#define NT 32  // 4096/128 tiles per dim

typedef __attribute__((ext_vector_type(8))) short short8;
typedef __attribute__((ext_vector_type(4))) float floatx4;
typedef __attribute__((ext_vector_type(4))) unsigned short ushortx4;

__device__ __forceinline__ unsigned short f2bf(float f) {
  unsigned u = __float_as_uint(f);
  u = u + 0x7FFFu + ((u >> 16) & 1u);  // RNE
  return (unsigned short)(u >> 16);
}

// ---------------- ae_loss + row sqnorm of y_true + fused bf16 convert ----------------
__global__ __launch_bounds__(256) void ae_sq_kernel(const float* __restrict__ yt,
                                                    const float* __restrict__ yp,
                                                    float* __restrict__ out,
                                                    float* __restrict__ sqD,
                                                    unsigned short* __restrict__ Xb) {
  int row = blockIdx.x, tid = threadIdx.x;
  const float4* a = (const float4*)(yt + (size_t)row * DD);
  const float4* b = (const float4*)(yp + (size_t)row * DD);
  float4 va = a[tid], vb = b[tid];
  ushortx4 o = {f2bf(va.x), f2bf(va.y), f2bf(va.z), f2bf(va.w)};
  *(ushortx4*)(Xb + (size_t)row * DD + tid * 4) = o;
  float e0 = va.x - vb.x, e1 = va.y - vb.y, e2 = va.z - vb.z, e3 = va.w - vb.w;
  float se = e0 * e0 + e1 * e1 + e2 * e2 + e3 * e3;
  float ss = va.x * va.x + va.y * va.y + va.z * va.z + va.w * va.w;
  for (int off = 32; off > 0; off >>= 1) {
    se += __shfl_down(se, off);
    ss += __shfl_down(ss, off);
  }
  __shared__ float sse[4], sss[4];
  int lane = tid & 63, w = tid >> 6;
  if (lane == 0) { sse[w] = se; sss[w] = ss; }
  __syncthreads();
  if (tid == 0) {
    out[row] = (sse[0] + sse[1] + sse[2] + sse[3]) * (1.0f / DD);
    sqD[row] = sss[0] + sss[1] + sss[2] + sss[3];
  }
}

__global__ __launch_bounds__(256) void sql_kernel(const float* __restrict__ lat,
                                                  float* __restrict__ sqL,
                                                  unsigned short* __restrict__ Lb) {
  int row = blockIdx.x * 4 + (threadIdx.x >> 6);
  int lane = threadIdx.x & 63;
  float v = lat[(size_t)row * DL + lane];
  Lb[(size_t)row * DL + lane] = f2bf(v);
  float s = v * v;
  for (int off = 32; off > 0; off >>= 1) s += __shfl_down(s, off);
  if (lane == 0) sqL[row] = s;
}

// ---------------- max of sq per space (no atomics; one block per space) ----------------
__global__ __launch_bounds__(1024) void norm_kernel(const float* __restrict__ sqD,
                                                    const float* __restrict__ sqL,
                                                    unsigned int* __restrict__ normbits) {
  const float* s = blockIdx.x ? sqL : sqD;
  int tid = threadIdx.x;
  float m = fmaxf(fmaxf(s[tid], s[tid + 1024]), fmaxf(s[tid + 2048], s[tid + 3072]));
  for (int off = 32; off > 0; off >>= 1) m = fmaxf(m, __shfl_down(m, off));
  __shared__ float sm[16];
  int lane = tid & 63, w = tid >> 6;
  if (lane == 0) sm[w] = m;
  __syncthreads();
  if (tid == 0) {
    float mm = sm[0];
    for (int k = 1; k < 16; ++k) mm = fmaxf(mm, sm[k]);
    normbits[blockIdx.x] = __float_as_uint(mm);
  }
}

// ---------------- bf16 MFMA distance gemm -> scaled-u16 matrices ----------------
// u16 = d * 65535 / (2*max||x||)  (monotone fixed-point; ~0.002 abs spacing for
// this data vs 0.125 for the bf16 grid -> far fewer tie-collisions vs reference).
__global__ __launch_bounds__(256) void dist_mfma(const unsigned short* __restrict__ Xb,
                                                 const unsigned short* __restrict__ Lb,
                                                 const float* __restrict__ sqD,
                                                 const float* __restrict__ sqL,
                                                 unsigned short* __restrict__ dD,
                                                 unsigned short* __restrict__ dL,
                                                 const unsigned int* __restrict__ normbits,
                                                 unsigned int* __restrict__ maxbits) {
  int inst = blockIdx.y;
  const unsigned short* X = inst ? Lb : Xb;
  const float* sq = inst ? sqL : sqD;
  unsigned short* dist = inst ? dL : dD;
  int K = inst ? DL : DD;
  float scale = 65535.0f / (2.0f * sqrtf(__uint_as_float(normbits[inst])) + 1e-12f);

  int bi = 0, rem = blockIdx.x, span = NT;  // triangular decode, bi <= bj
  while (rem >= span) { rem -= span; ++bi; --span; }
  int bj = bi + rem;
  int row0 = bi * 128, col0 = bj * 128;

  __shared__ short As[128 * 40];  // row stride 40 (16B-aligned frags, 2-way banks)
  __shared__ short Bs[128 * 40];
  int tid = threadIdx.x;
  int wave = tid >> 6, lane = tid & 63;
  int m = lane & 15, q = lane >> 4;
  int rw = (wave >> 1) * 64, cw = (wave & 1) * 64;

  floatx4 acc[4][4];
#pragma unroll
  for (int mi = 0; mi < 4; ++mi)
#pragma unroll
    for (int ni = 0; ni < 4; ++ni) acc[mi][ni] = {0.f, 0.f, 0.f, 0.f};

  int s0 = tid, s1 = tid + 256;  // 512 segs/side: row = s>>2, part = s&3
  int r0 = s0 >> 2, p0 = s0 & 3, r1 = s1 >> 2, p1 = s1 & 3;

  for (int k0 = 0; k0 < K; k0 += 32) {
    short8 a0 = *(const short8*)(X + (size_t)(row0 + r0) * K + k0 + p0 * 8);
    short8 a1 = *(const short8*)(X + (size_t)(row0 + r1) * K + k0 + p1 * 8);
    short8 b0 = *(const short8*)(X + (size_t)(col0 + r0) * K + k0 + p0 * 8);
    short8 b1 = *(const short8*)(X + (size_t)(col0 + r1) * K + k0 + p1 * 8);
    __syncthreads();
    *(short8*)&As[r0 * 40 + p0 * 8] = a0;
    *(short8*)&As[r1 * 40 + p1 * 8] = a1;
    *(short8*)&Bs[r0 * 40 + p0 * 8] = b0;
    *(short8*)&Bs[r1 * 40 + p1 * 8] = b1;
    __syncthreads();
    short8 aF[4], bF[4];
#pragma unroll
    for (int mi = 0; mi < 4; ++mi)
      aF[mi] = *(const short8*)&As[(rw + mi * 16 + m) * 40 + q * 8];
#pragma unroll
    for (int ni = 0; ni < 4; ++ni)
      bF[ni] = *(const short8*)&Bs[(cw + ni * 16 + m) * 40 + q * 8];
#pragma unroll
    for (int mi = 0; mi < 4; ++mi)
#pragma unroll
      for (int ni = 0; ni < 4; ++ni)
        acc[mi][ni] = __builtin_amdgcn_mfma_f32_16x16x32_bf16(aF[mi], bF[ni],
                                                              acc[mi][ni], 0, 0, 0);
  }

  float bmax = 0.f;
#pragma unroll
  for (int mi = 0; mi < 4; ++mi) {
    int i0 = row0 + rw + mi * 16 + q * 4;
    float s_i[4] = {sq[i0], sq[i0 + 1], sq[i0 + 2], sq[i0 + 3]};
#pragma unroll
    for (int ni = 0; ni < 4; ++ni) {
      int j = col0 + cw + ni * 16 + m;
      float sj = sq[j];
      ushortx4 tvec;
#pragma unroll
      for (int r = 0; r < 4; ++r) {
        float d2 = s_i[r] + sj - 2.f * acc[mi][ni][r];
        float d = d2 > 0.f ? sqrtf(d2) : 0.f;
        bmax = fmaxf(bmax, d);
        unsigned short u = (unsigned short)fminf(d * scale, 65535.0f);
        dist[(size_t)(i0 + r) * N_PTS + j] = u;  // upper
        tvec[r] = u;
      }
      *(ushortx4*)&dist[(size_t)j * N_PTS + i0] = tvec;  // lower, 8B store
    }
  }
  if (inst == 0) {  // exact-pipeline max of data distances (for loss normalization)
    for (int off = 32; off > 0; off >>= 1) bmax = fmaxf(bmax, __shfl_down(bmax, off));
    __shared__ float bm[4];
    if (lane == 0) bm[wave] = bmax;
    __syncthreads();
    if (tid == 0)
      atomicMax(maxbits, __float_as_uint(fmaxf(fmaxf(bm[0], bm[1]), fmaxf(bm[2], bm[3]))));
  }
}

// ---------------- Boruvka MST on u16 matrices ----------------
// Edge total order: key = dist16<<24 | min(i,j)<<12 | max(i,j)  (unique).

__global__ __launch_bounds__(256) void boruvka_init(unsigned short* __restrict__ comp,
                                                    unsigned long long* __restrict__ bestKey,
                                                    int* __restrict__ numRoots,
                                                    int* __restrict__ edgeCnt) {
  int i = blockIdx.x * 256 + threadIdx.x;
  if (i < N_PTS) {
    comp[i] = (unsigned short)i;
    comp[N_PTS + i] = (unsigned short)i;
    bestKey[i] = ~0ULL;
    bestKey[N_PTS + i] = ~0ULL;
  }
  if (i == 0) {
    numRoots[0] = N_PTS; numRoots[1] = N_PTS;
    edgeCnt[0] = 0; edgeCnt[1] = 0;
  }
}

// 16 rows per block (4 per wave); ushort8 row reads; comps in LDS.
__global__ __launch_bounds__(256) void boruvka_scan(const unsigned short* __restrict__ dD,
                                                    const unsigned short* __restrict__ dL,
                                                    const unsigned short* __restrict__ comp,
                                                    unsigned long long* __restrict__ bestKey,
                                                    const int* __restrict__ numRoots) {
  int inst = blockIdx.y;
  if (numRoots[inst] <= 1) return;
  const unsigned short* dist = inst ? dL : dD;
  comp += (size_t)inst * N_PTS;
  bestKey += (size_t)inst * N_PTS;
  __shared__ unsigned short comp_s[N_PTS];
  int tid = threadIdx.x;
  for (int i = tid; i < N_PTS; i += 256) comp_s[i] = comp[i];
  __syncthreads();
  int wave = tid >> 6, lane = tid & 63;
  for (int rr = 0; rr < 4; ++rr) {
    int row = blockIdx.x * 16 + wave * 4 + rr;
    unsigned myc = comp_s[row];
    const uint4* r8 = (const uint4*)(dist + (size_t)row * N_PTS);
    unsigned bb = 0xFFFFFFFFu;
    int bj = N_PTS;
    for (int t = 0; t < 8; ++t) {
      int idx = lane + t * 64;  // 8 cols per uint4
      uint4 v = r8[idx];
      uint4 cc = *(const uint4*)&comp_s[idx * 8];
      int j0 = idx * 8;
      unsigned d0 = v.x & 0xFFFFu, d1 = v.x >> 16, d2 = v.y & 0xFFFFu, d3 = v.y >> 16;
      unsigned d4 = v.z & 0xFFFFu, d5 = v.z >> 16, d6 = v.w & 0xFFFFu, d7 = v.w >> 16;
      unsigned c0 = cc.x & 0xFFFFu, c1 = cc.x >> 16, c2 = cc.y & 0xFFFFu, c3 = cc.y >> 16;
      unsigned c4 = cc.z & 0xFFFFu, c5 = cc.z >> 16, c6 = cc.w & 0xFFFFu, c7 = cc.w >> 16;
      if (c0 != myc && d0 < bb) { bb = d0; bj = j0 + 0; }
      if (c1 != myc && d1 < bb) { bb = d1; bj = j0 + 1; }
      if (c2 != myc && d2 < bb) { bb = d2; bj = j0 + 2; }
      if (c3 != myc && d3 < bb) { bb = d3; bj = j0 + 3; }
      if (c4 != myc && d4 < bb) { bb = d4; bj = j0 + 4; }
      if (c5 != myc && d5 < bb) { bb = d5; bj = j0 + 5; }
      if (c6 != myc && d6 < bb) { bb = d6; bj = j0 + 6; }
      if (c7 != myc && d7 < bb) { bb = d7; bj = j0 + 7; }
    }
    for (int off = 32; off > 0; off >>= 1) {
      unsigned ob = __shfl_down(bb, off);
      int oj = __shfl_down(bj, off);
      if (ob < bb || (ob == bb && oj < bj)) { bb = ob; bj = oj; }
    }
    if (lane == 0 && bj < N_PTS) {
      int lo = row < bj ? row : bj, hi = row < bj ? bj : row;
      unsigned long long key = ((unsigned long long)bb << 24) |
                               ((unsigned long long)lo << 12) | (unsigned long long)hi;
      atomicMin(&bestKey[myc], key);
    }
  }
}

// One block per instance, 1024 threads. Race-free: snapshot bestKey into LDS
// before reset; mutual 2-cycles share one edge -> smaller root keeps it.
__global__ __launch_bounds__(1024) void boruvka_merge(unsigned short* __restrict__ comp,
                                                      unsigned long long* __restrict__ bestKey,
                                                      int* __restrict__ numRoots,
                                                      int2* __restrict__ edges,
                                                      int* __restrict__ edgeCnt) {
  int inst = blockIdx.x;
  if (numRoots[inst] <= 1) return;
  comp += (size_t)inst * N_PTS;
  bestKey += (size_t)inst * N_PTS;
  edges += (size_t)inst * NEDGE;
  __shared__ unsigned short comp_s[N_PTS];
  __shared__ int parent_s[N_PTS];
  __shared__ unsigned long long key_s[N_PTS];
  __shared__ int rootCnt;
  int tid = threadIdx.x;
  if (tid == 0) rootCnt = 0;
  for (int i = tid; i < N_PTS; i += 1024) {
    comp_s[i] = comp[i];
    key_s[i] = bestKey[i];
    bestKey[i] = ~0ULL;
  }
  __syncthreads();
  for (int c = tid; c < N_PTS; c += 1024) {
    int p = c;
    if (comp_s[c] == c) {  // root
      unsigned long long key = key_s[c];
      if (key != ~0ULL) {
        int lo = (int)((key >> 12) & 0xFFF), hi = (int)(key & 0xFFF);
        int c2 = (comp_s[lo] == c) ? comp_s[hi] : comp_s[lo];
        bool mutual = (key_s[c2] == key);
        bool add;
        if (mutual) {
          if (c < c2) add = true;
          else { p = c2; add = false; }
        } else { p = c2; add = true; }
        if (add) {
          int idx = atomicAdd(&edgeCnt[inst], 1);
          if (idx < NEDGE) edges[idx] = make_int2(lo, hi);
        }
      }
    }
    parent_s[c] = p;
  }
  __syncthreads();
  for (int it = 0; it < 12; ++it) {  // pointer jumping (monotone races)
    for (int c = tid; c < N_PTS; c += 1024) parent_s[c] = parent_s[parent_s[c]];
    __syncthreads();
  }
  int local = 0;
  for (int c = tid; c < N_PTS; c += 1024) {
    comp[c] = (unsigned short)parent_s[comp_s[c]];
    if (comp_s[c] == c && parent_s[c] == c) local++;
  }
  atomicAdd(&rootCnt, local);
  __syncthreads();
  if (tid == 0) numRoots[inst] = rootCnt;
}

// ---------------- edge gather + topo losses ----------------
// 8 edges per wave, register accumulation, LDS reduce, 2 atomics per block
// (512 total vs 8190 single-address atomics that bounded Round 4 at 110 us).
__global__ __launch_bounds__(256) void loss_kernel(const float* __restrict__ yt,
                                                   const float* __restrict__ lat,
                                                   const float* __restrict__ sqD,
                                                   const float* __restrict__ sqL,
                                                   const int2* __restrict__ edges_all,
                                                   const unsigned int* __restrict__ maxbits,
                                                   const float* __restrict__ latent_norm,
                                                   float* __restrict__ sums) {
  int wave = threadIdx.x >> 6, lane = threadIdx.x & 63;
  int g = blockIdx.x * 4 + wave;
  float inv_md = 1.f / __uint_as_float(*maxbits);
  float inv_ln = 1.f / latent_norm[0];
  float acc0 = 0.f, acc1 = 0.f;
  for (int t = 0; t < 8; ++t) {
    int e = g * 8 + t;
    if (e >= 2 * NEDGE) break;
    int2 ed = edges_all[e];
    int i = ed.x & (N_PTS - 1), j = ed.y & (N_PTS - 1);
    const float4* ai = (const float4*)(yt + (size_t)i * DD);
    const float4* aj = (const float4*)(yt + (size_t)j * DD);
    float dot = 0.f;
#pragma unroll
    for (int tt = 0; tt < 4; ++tt) {
      float4 x = ai[lane + tt * 64], y = aj[lane + tt * 64];
      dot += x.x * y.x + x.y * y.y + x.z * y.z + x.w * y.w;
    }
    float li = lat[(size_t)i * DL + lane], lj = lat[(size_t)j * DL + lane];
    float dotl = li * lj;
    for (int off = 32; off > 0; off >>= 1) {
      dot += __shfl_down(dot, off);
      dotl += __shfl_down(dotl, off);
    }
    if (lane == 0) {
      float d2 = sqD[i] + sqD[j] - 2.f * dot;
      float dd = (d2 > 0.f ? sqrtf(d2) : 0.f) * inv_md;
      float l2 = sqL[i] + sqL[j] - 2.f * dotl;
      float ld = (l2 > 0.f ? sqrtf(l2) : 0.f) * inv_ln;
      float df = dd - ld;
      if (e < NEDGE) acc0 += df * df; else acc1 += df * df;
    }
  }
  __shared__ float s0[4], s1[4];
  if (lane == 0) { s0[wave] = acc0; s1[wave] = acc1; }
  __syncthreads();
  if (threadIdx.x == 0) {
    float t0 = s0[0] + s0[1] + s0[2] + s0[3];
    float t1 = s1[0] + s1[1] + s1[2] + s1[3];
    if (t0 != 0.f) atomicAdd(&sums[0], t0);
    if (t1 != 0.f) atomicAdd(&sums[1], t1);
  }
}

__global__ __launch_bounds__(256) void finalize_kernel(float* __restrict__ out,
                                                       const float* __restrict__ sums) {
  int i = blockIdx.x * blockDim.x + threadIdx.x;
  float topo = (sums[0] + sums[1]) * (1.0f / NEDGE);
  out[i] += 0.5f * topo;  // REG_LAMBDA
}

extern "C" void kernel_launch(void* const* d_in, const int* in_sizes, int n_in,
                              void* d_out, int out_size, void* d_ws, size_t ws_size,
                              hipStream_t stream) {
  const float* y_true = (const float*)d_in[0];
  const float* latent = (const float*)d_in[1];
  const float* y_pred = (const float*)d_in[2];
  const float* latent_norm = (const float*)d_in[3];
  float* out = (float*)d_out;
  char* ws = (char*)d_ws;

  const size_t MAT16 = (size_t)N_PTS * N_PTS * 2;  // 32 MB per u16 matrix
  size_t off = 0;
  unsigned short* dD = (unsigned short*)(ws + off); off += MAT16;
  unsigned short* dL = (unsigned short*)(ws + off); off += MAT16;
  unsigned short* Xb = (unsigned short*)(ws + off); off += (size_t)N_PTS * DD * 2;
  unsigned short* Lb = (unsigned short*)(ws + off); off += (size_t)N_PTS * DL * 2;
  float* sqD = (float*)(ws + off); off += (size_t)N_PTS * 4;
  float* sqL = (float*)(ws + off); off += (size_t)N_PTS * 4;
  int2* edges = (int2*)(ws + off); off += (size_t)2 * NEDGE * 8 + 16;
  unsigned long long* bestKey = (unsigned long long*)(ws + off); off += (size_t)2 * N_PTS * 8;
  unsigned short* comp = (unsigned short*)(ws + off); off += (size_t)2 * N_PTS * 2;
  int* numRoots = (int*)(ws + off); off += 256;
  int* edgeCnt = numRoots + 2;
  unsigned int* maxbits = (unsigned int*)(edgeCnt + 2);
  float* sums = (float*)(maxbits + 1);
  unsigned int* normbits = (unsigned int*)(sums + 2);

  hipMemsetAsync(numRoots, 0, 256, stream);

  ae_sq_kernel<<<N_PTS, 256, 0, stream>>>(y_true, y_pred, out, sqD, Xb);
  sql_kernel<<<N_PTS / 4, 256, 0, stream>>>(latent, sqL, Lb);
  norm_kernel<<<2, 1024, 0, stream>>>(sqD, sqL, normbits);
  boruvka_init<<<N_PTS / 256, 256, 0, stream>>>(comp, bestKey, numRoots, edgeCnt);

  int tri = NT * (NT + 1) / 2;  // 528
  dist_mfma<<<dim3(tri, 2), 256, 0, stream>>>(Xb, Lb, sqD, sqL, dD, dL, normbits, maxbits);

  for (int r = 0; r < B_ROUNDS; ++r) {
    boruvka_scan<<<dim3(N_PTS / 16, 2), 256, 0, stream>>>(dD, dL, comp, bestKey, numRoots);
    boruvka_merge<<<2, 1024, 0, stream>>>(comp, bestKey, numRoots, edges, edgeCnt);
  }
  loss_kernel<<<256, 256, 0, stream>>>(y_true, latent, sqD, sqL, edges,
                                       maxbits, latent_norm, sums);
  finalize_kernel<<<N_PTS / 256, 256, 0, stream>>>(out, sums);
}